// Round 2
// baseline (1113.746 us; speedup 1.0000x reference)
//
#include <hip/hip_runtime.h>

#define NN 50000
#define NE 600000
#define HD 128

typedef __attribute__((ext_vector_type(8))) short short8;
typedef __attribute__((ext_vector_type(4))) float floatx4;
typedef __attribute__((ext_vector_type(2))) float floatx2;

__device__ __forceinline__ unsigned short f2bf(float f) {
  unsigned int u = __builtin_bit_cast(unsigned int, f);
  u += 0x7FFFu + ((u >> 16) & 1u);
  return (unsigned short)(u >> 16);
}

// Convert 8 consecutive f32 -> bf16 fragment (two float4 loads).
__device__ __forceinline__ short8 cvt8(const float* __restrict__ p) {
  floatx4 v0 = *(const floatx4*)p;
  floatx4 v1 = *(const floatx4*)(p + 4);
  short8 r;
  r[0] = (short)f2bf(v0[0]); r[1] = (short)f2bf(v0[1]);
  r[2] = (short)f2bf(v0[2]); r[3] = (short)f2bf(v0[3]);
  r[4] = (short)f2bf(v1[0]); r[5] = (short)f2bf(v1[1]);
  r[6] = (short)f2bf(v1[2]); r[7] = (short)f2bf(v1[3]);
  return r;
}

// Pack W[K][128] f32 row-major -> bf16 in MFMA B-fragment order:
// wp[((k0*8+n0)*64 + lane)*8 + j] = W[k0*32 + (lane>>4)*8 + j][n0*16 + (lane&15)]
__device__ __forceinline__ void pack_one(const float* __restrict__ w,
                                         unsigned short* __restrict__ wp, int p) {
  int j = p & 7, lane = (p >> 3) & 63, t = p >> 9;
  int n0 = t & 7, k0 = t >> 3;
  int k = k0 * 32 + (lane >> 4) * 8 + j;
  int n = n0 * 16 + (lane & 15);
  wp[p] = f2bf(w[k * HD + n]);
}

// Fused prep: pack all 6 weights + zero CSR counters + convert x->bf16.
// elem ranges: [0,147456) weights, [147456,197456) cnt, [197456,997456) cvt.
__global__ void prep_kernel(const float* __restrict__ we0, const float* __restrict__ we1,
                            const float* __restrict__ we2, const float* __restrict__ wn0,
                            const float* __restrict__ wn1, const float* __restrict__ wn2,
                            unsigned short* __restrict__ wpack,
                            const float* __restrict__ x, unsigned short* __restrict__ xb,
                            int* __restrict__ cnt, int do_cnt, int do_cvt) {
  int p = blockIdx.x * 256 + threadIdx.x;
  if (p < 147456) {
    const float* src;
    int rel;
    if (p < 49152) { src = we0; rel = p; }
    else if (p < 65536) { src = we1; rel = p - 49152; }
    else if (p < 81920) { src = we2; rel = p - 65536; }
    else if (p < 114688) { src = wn0; rel = p - 81920; }
    else if (p < 131072) { src = wn1; rel = p - 114688; }
    else { src = wn2; rel = p - 131072; }
    pack_one(src, wpack + (p - rel), rel);
  } else if (p < 197456) {
    if (do_cnt) cnt[p - 147456] = 0;
  } else if (p < 997456) {
    if (do_cvt) {
      int q = p - 197456;
      *(short8*)(xb + (size_t)q * 8) = cvt8(x + (size_t)q * 8);
    }
  }
}

__global__ void hist_kernel(const int* __restrict__ idx, int* __restrict__ cnt) {
  int eid = blockIdx.x * 256 + threadIdx.x;
  if (eid < NE) atomicAdd(&cnt[idx[NE + eid]], 1);
}

// Single-block exclusive scan of cnt[0..NN) -> offs (NN+1) and cur (cursor copy).
__global__ __launch_bounds__(1024) void scan_kernel(const int* __restrict__ cnt,
                                                    int* __restrict__ offs,
                                                    int* __restrict__ cur) {
  __shared__ int part[1024];
  int t = threadIdx.x;
  int base = t * 49;
  int s = 0;
  for (int i = 0; i < 49; ++i) {
    int g = base + i;
    if (g < NN) s += cnt[g];
  }
  part[t] = s;
  __syncthreads();
  for (int off = 1; off < 1024; off <<= 1) {
    int add = (t >= off) ? part[t - off] : 0;
    __syncthreads();
    part[t] += add;
    __syncthreads();
  }
  int run = part[t] - s;  // exclusive prefix of this thread's chunk
  for (int i = 0; i < 49; ++i) {
    int g = base + i;
    if (g < NN) {
      int c = cnt[g];
      offs[g] = run;
      cur[g] = run;
      run += c;
    }
  }
  if (t == 1023) offs[NN] = run;
}

__global__ void fill_kernel(const int* __restrict__ idx, int* __restrict__ cur,
                            int* __restrict__ perm) {
  int eid = blockIdx.x * 256 + threadIdx.x;
  if (eid < NE) {
    int d = idx[NE + eid];
    int pos = atomicAdd(&cur[d], 1);
    perm[pos] = eid;
  }
}

// LDS-sourced GEMM for a wave's 16 rows x 128 cols (layers 1/2).
template <int KSTEPS>
__device__ __forceinline__ void gemm_tile(const unsigned short* a_base, int a_stride,
                                          const unsigned short* __restrict__ wp,
                                          int lane, floatx4* acc) {
  int quad = lane >> 4, l16 = lane & 15;
  for (int k0 = 0; k0 < KSTEPS; ++k0) {
    short8 a = *(const short8*)(a_base + l16 * a_stride + k0 * 32 + quad * 8);
    const unsigned short* w = wp + k0 * 4096 + lane * 8;
#pragma unroll
    for (int n0 = 0; n0 < 8; ++n0) {
      short8 b = *(const short8*)(w + n0 * 512);
      acc[n0] = __builtin_amdgcn_mfma_f32_16x16x32_bf16(a, b, acc[n0], 0, 0, 0);
    }
  }
}

__device__ __forceinline__ void store_relu_bf16(const floatx4* acc,
                                                const float* __restrict__ bias,
                                                unsigned short* out_base, int stride,
                                                int lane) {
  int quad = lane >> 4, l16 = lane & 15;
#pragma unroll
  for (int n0 = 0; n0 < 8; ++n0) {
    float bv = bias[n0 * 16 + l16];
#pragma unroll
    for (int r = 0; r < 4; ++r) {
      float v = acc[n0][r] + bv;
      v = v > 0.f ? v : 0.f;
      out_base[(quad * 4 + r) * stride + n0 * 16 + l16] = f2bf(v);
    }
  }
}

#define SH 136  // 128 + 8 pad

// XBF: x pre-converted to bf16. ATOM: legacy atomic scatter-add into agg.
template <int XBF, int ATOM>
__global__ __launch_bounds__(256, 4) void edge_kernel(
    const float* __restrict__ x, const unsigned short* __restrict__ xb,
    const float* __restrict__ e, const int* __restrict__ idx,
    const unsigned short* __restrict__ w0p, const float* __restrict__ b0,
    const unsigned short* __restrict__ w1p, const float* __restrict__ b1,
    const unsigned short* __restrict__ w2p, const float* __restrict__ b2,
    const float* __restrict__ g, const float* __restrict__ bg,
    float* __restrict__ e_out, float* __restrict__ agg) {
  __shared__ __align__(16) unsigned short lh[64 * SH];  // per-wave regions

  int wave = threadIdx.x >> 6, lane = threadIdx.x & 63;
  int quad = lane >> 4, l16 = lane & 15;
  int ebase = blockIdx.x * 64 + wave * 16;  // this wave's first edge
  int arow = ebase + l16;                   // this lane's A row (by l16)
  int s = idx[arow], d = idx[NE + arow];

  floatx4 acc[8];
  floatx4 z = {0.f, 0.f, 0.f, 0.f};
#pragma unroll
  for (int t = 0; t < 8; ++t) acc[t] = z;

  // layer0: [16,384] @ [384,128]. A fragments straight from global:
  // K 0..127 = x[dst], 128..255 = x[src], 256..383 = e[ei].
  const float* ee = e + (size_t)arow * HD + quad * 8;
  if constexpr (XBF) {
    const unsigned short* xd = xb + (size_t)d * HD + quad * 8;
    const unsigned short* xs = xb + (size_t)s * HD + quad * 8;
#pragma unroll
    for (int k0 = 0; k0 < 12; ++k0) {
      short8 a;
      if (k0 < 4)
        a = *(const short8*)(xd + k0 * 32);
      else if (k0 < 8)
        a = *(const short8*)(xs + (k0 - 4) * 32);
      else
        a = cvt8(ee + (k0 - 8) * 32);
      const unsigned short* w = w0p + k0 * 4096 + lane * 8;
#pragma unroll
      for (int n0 = 0; n0 < 8; ++n0) {
        short8 b = *(const short8*)(w + n0 * 512);
        acc[n0] = __builtin_amdgcn_mfma_f32_16x16x32_bf16(a, b, acc[n0], 0, 0, 0);
      }
    }
  } else {
    const float* xd = x + (size_t)d * HD + quad * 8;
    const float* xs = x + (size_t)s * HD + quad * 8;
#pragma unroll
    for (int k0 = 0; k0 < 12; ++k0) {
      short8 a;
      if (k0 < 4)
        a = cvt8(xd + k0 * 32);
      else if (k0 < 8)
        a = cvt8(xs + (k0 - 4) * 32);
      else
        a = cvt8(ee + (k0 - 8) * 32);
      const unsigned short* w = w0p + k0 * 4096 + lane * 8;
#pragma unroll
      for (int n0 = 0; n0 < 8; ++n0) {
        short8 b = *(const short8*)(w + n0 * 512);
        acc[n0] = __builtin_amdgcn_mfma_f32_16x16x32_bf16(a, b, acc[n0], 0, 0, 0);
      }
    }
  }
  unsigned short* lhw = lh + wave * 16 * SH;
  store_relu_bf16(acc, b0, lhw, SH, lane);

  // layer1: in-place (per-wave region; DS ops complete in order -> no barriers).
#pragma unroll
  for (int t = 0; t < 8; ++t) acc[t] = z;
  gemm_tile<4>(lhw, SH, w1p, lane, acc);
  store_relu_bf16(acc, b1, lhw, SH, lane);

  // layer2: keep in regs
#pragma unroll
  for (int t = 0; t < 8; ++t) acc[t] = z;
  gemm_tile<4>(lhw, SH, w2p, lane, acc);

  // bias + LayerNorm (rows r_local = quad*4+r, cols n0*16+l16)
  float h3[8][4];
#pragma unroll
  for (int n0 = 0; n0 < 8; ++n0) {
    float bv = b2[n0 * 16 + l16];
#pragma unroll
    for (int r = 0; r < 4; ++r) h3[n0][r] = acc[n0][r] + bv;
  }
  float s1[4] = {0.f, 0.f, 0.f, 0.f}, s2[4] = {0.f, 0.f, 0.f, 0.f};
#pragma unroll
  for (int n0 = 0; n0 < 8; ++n0)
#pragma unroll
    for (int r = 0; r < 4; ++r) {
      s1[r] += h3[n0][r];
      s2[r] += h3[n0][r] * h3[n0][r];
    }
#pragma unroll
  for (int m = 1; m < 16; m <<= 1) {
#pragma unroll
    for (int r = 0; r < 4; ++r) {
      s1[r] += __shfl_xor(s1[r], m, 64);
      s2[r] += __shfl_xor(s2[r], m, 64);
    }
  }
  float mu[4], rs[4];
#pragma unroll
  for (int r = 0; r < 4; ++r) {
    mu[r] = s1[r] * (1.f / 128.f);
    float var = s2[r] * (1.f / 128.f) - mu[r] * mu[r];
    rs[r] = rsqrtf(var + 1e-5f);
  }
  // write e_new (+ legacy atomic scatter if ATOM)
#pragma unroll
  for (int n0 = 0; n0 < 8; ++n0) {
    int col = n0 * 16 + l16;
    float gv = g[col], bv = bg[col];
#pragma unroll
    for (int r = 0; r < 4; ++r) {
      int ei = ebase + quad * 4 + r;
      float v = (h3[n0][r] - mu[r]) * rs[r] * gv + bv;
      e_out[(size_t)ei * HD + col] = v;
      if constexpr (ATOM) {
        int drow = idx[NE + ei];
        atomicAdd(&agg[(size_t)drow * HD + col], v);
      }
    }
  }
}

// CSR-gather node kernel: aggregates incoming e_out rows per node in registers,
// stages bf16 agg rows in LDS, then runs the node MLP.
template <int XBF>
__global__ __launch_bounds__(256, 4) void node_kernel_csr(
    const float* __restrict__ x, const unsigned short* __restrict__ xb,
    const float* __restrict__ e_out, const int* __restrict__ offs,
    const int* __restrict__ perm, const unsigned short* __restrict__ w0p,
    const float* __restrict__ b0, const unsigned short* __restrict__ w1p,
    const float* __restrict__ b1, const unsigned short* __restrict__ w2p,
    const float* __restrict__ b2, const float* __restrict__ g,
    const float* __restrict__ bg, float* __restrict__ x_out) {
  __shared__ __align__(16) unsigned short lh[64 * SH];   // 17408 B
  __shared__ __align__(16) unsigned short sag[64 * SH];  // 17408 B (agg rows bf16)

  int wave = threadIdx.x >> 6, lane = threadIdx.x & 63;
  int quad = lane >> 4, l16 = lane & 15;
  int nbase = blockIdx.x * 64 + wave * 16;

  // --- aggregation: 16 rows, lane owns cols c0,c0+1; 4-deep load pipeline ---
  unsigned short* sagw = sag + wave * 16 * SH;
  int c0 = lane * 2;
  for (int rr = 0; rr < 16; ++rr) {
    int n = nbase + rr;
    float a0 = 0.f, a1 = 0.f;
    if (n < NN) {
      int beg = offs[n], end = offs[n + 1];
      int j = beg;
      for (; j + 4 <= end; j += 4) {
        int e0 = perm[j], e1 = perm[j + 1], e2 = perm[j + 2], e3 = perm[j + 3];
        floatx2 v0 = *(const floatx2*)(e_out + (size_t)e0 * HD + c0);
        floatx2 v1 = *(const floatx2*)(e_out + (size_t)e1 * HD + c0);
        floatx2 v2 = *(const floatx2*)(e_out + (size_t)e2 * HD + c0);
        floatx2 v3 = *(const floatx2*)(e_out + (size_t)e3 * HD + c0);
        a0 += v0[0] + v1[0] + v2[0] + v3[0];
        a1 += v0[1] + v1[1] + v2[1] + v3[1];
      }
      for (; j < end; ++j) {
        int eid = perm[j];
        floatx2 v = *(const floatx2*)(e_out + (size_t)eid * HD + c0);
        a0 += v[0];
        a1 += v[1];
      }
    }
    unsigned int pk = (unsigned int)f2bf(a0) | ((unsigned int)f2bf(a1) << 16);
    *(unsigned int*)(sagw + rr * SH + c0) = pk;
  }
  // no barrier: per-wave LDS region, wave-synchronous lanes.

  int arow = nbase + l16;
  int nc = arow < NN ? arow : NN - 1;

  floatx4 acc[8];
  floatx4 z = {0.f, 0.f, 0.f, 0.f};
#pragma unroll
  for (int t = 0; t < 8; ++t) acc[t] = z;

  // layer0: [16,256] @ [256,128]. K 0..127 = x[n] (global), 128..255 = agg (LDS).
#pragma unroll
  for (int k0 = 0; k0 < 8; ++k0) {
    short8 a;
    if (k0 < 4) {
      if constexpr (XBF)
        a = *(const short8*)(xb + (size_t)nc * HD + quad * 8 + k0 * 32);
      else
        a = cvt8(x + (size_t)nc * HD + quad * 8 + k0 * 32);
    } else {
      a = *(const short8*)(sagw + l16 * SH + (k0 - 4) * 32 + quad * 8);
    }
    const unsigned short* w = w0p + k0 * 4096 + lane * 8;
#pragma unroll
    for (int n0 = 0; n0 < 8; ++n0) {
      short8 b = *(const short8*)(w + n0 * 512);
      acc[n0] = __builtin_amdgcn_mfma_f32_16x16x32_bf16(a, b, acc[n0], 0, 0, 0);
    }
  }
  unsigned short* lhw = lh + wave * 16 * SH;
  store_relu_bf16(acc, b0, lhw, SH, lane);

#pragma unroll
  for (int t = 0; t < 8; ++t) acc[t] = z;
  gemm_tile<4>(lhw, SH, w1p, lane, acc);
  store_relu_bf16(acc, b1, lhw, SH, lane);

#pragma unroll
  for (int t = 0; t < 8; ++t) acc[t] = z;
  gemm_tile<4>(lhw, SH, w2p, lane, acc);

  float h3[8][4];
#pragma unroll
  for (int n0 = 0; n0 < 8; ++n0) {
    float bv = b2[n0 * 16 + l16];
#pragma unroll
    for (int r = 0; r < 4; ++r) h3[n0][r] = acc[n0][r] + bv;
  }
  float s1[4] = {0.f, 0.f, 0.f, 0.f}, s2[4] = {0.f, 0.f, 0.f, 0.f};
#pragma unroll
  for (int n0 = 0; n0 < 8; ++n0)
#pragma unroll
    for (int r = 0; r < 4; ++r) {
      s1[r] += h3[n0][r];
      s2[r] += h3[n0][r] * h3[n0][r];
    }
#pragma unroll
  for (int m = 1; m < 16; m <<= 1) {
#pragma unroll
    for (int r = 0; r < 4; ++r) {
      s1[r] += __shfl_xor(s1[r], m, 64);
      s2[r] += __shfl_xor(s2[r], m, 64);
    }
  }
  float mu[4], rs[4];
#pragma unroll
  for (int r = 0; r < 4; ++r) {
    mu[r] = s1[r] * (1.f / 128.f);
    float var = s2[r] * (1.f / 128.f) - mu[r] * mu[r];
    rs[r] = rsqrtf(var + 1e-5f);
  }
#pragma unroll
  for (int n0 = 0; n0 < 8; ++n0) {
    int col = n0 * 16 + l16;
    float gv = g[col], bv = bg[col];
#pragma unroll
    for (int r = 0; r < 4; ++r) {
      int ni = nbase + quad * 4 + r;
      if (ni < NN) {
        float v = (h3[n0][r] - mu[r]) * rs[r] * gv + bv;
        x_out[(size_t)ni * HD + col] = x[(size_t)ni * HD + col] + v;
      }
    }
  }
}

// Legacy node kernel reading a pre-computed agg array (atomic fallback path).
template <int XBF>
__global__ __launch_bounds__(256, 4) void node_kernel_atom(
    const float* __restrict__ x, const unsigned short* __restrict__ xb,
    const float* __restrict__ agg, const unsigned short* __restrict__ w0p,
    const float* __restrict__ b0, const unsigned short* __restrict__ w1p,
    const float* __restrict__ b1, const unsigned short* __restrict__ w2p,
    const float* __restrict__ b2, const float* __restrict__ g,
    const float* __restrict__ bg, float* __restrict__ x_out) {
  __shared__ __align__(16) unsigned short lh[64 * SH];

  int wave = threadIdx.x >> 6, lane = threadIdx.x & 63;
  int quad = lane >> 4, l16 = lane & 15;
  int nbase = blockIdx.x * 64 + wave * 16;
  int arow = nbase + l16;
  int nc = arow < NN ? arow : NN - 1;

  floatx4 acc[8];
  floatx4 z = {0.f, 0.f, 0.f, 0.f};
#pragma unroll
  for (int t = 0; t < 8; ++t) acc[t] = z;

  const float* ar = agg + (size_t)nc * HD + quad * 8;
#pragma unroll
  for (int k0 = 0; k0 < 8; ++k0) {
    short8 a;
    if (k0 < 4) {
      if constexpr (XBF)
        a = *(const short8*)(xb + (size_t)nc * HD + quad * 8 + k0 * 32);
      else
        a = cvt8(x + (size_t)nc * HD + quad * 8 + k0 * 32);
    } else {
      a = cvt8(ar + (k0 - 4) * 32);
    }
    const unsigned short* w = w0p + k0 * 4096 + lane * 8;
#pragma unroll
    for (int n0 = 0; n0 < 8; ++n0) {
      short8 b = *(const short8*)(w + n0 * 512);
      acc[n0] = __builtin_amdgcn_mfma_f32_16x16x32_bf16(a, b, acc[n0], 0, 0, 0);
    }
  }
  unsigned short* lhw = lh + wave * 16 * SH;
  store_relu_bf16(acc, b0, lhw, SH, lane);

#pragma unroll
  for (int t = 0; t < 8; ++t) acc[t] = z;
  gemm_tile<4>(lhw, SH, w1p, lane, acc);
  store_relu_bf16(acc, b1, lhw, SH, lane);

#pragma unroll
  for (int t = 0; t < 8; ++t) acc[t] = z;
  gemm_tile<4>(lhw, SH, w2p, lane, acc);

  float h3[8][4];
#pragma unroll
  for (int n0 = 0; n0 < 8; ++n0) {
    float bv = b2[n0 * 16 + l16];
#pragma unroll
    for (int r = 0; r < 4; ++r) h3[n0][r] = acc[n0][r] + bv;
  }
  float s1[4] = {0.f, 0.f, 0.f, 0.f}, s2[4] = {0.f, 0.f, 0.f, 0.f};
#pragma unroll
  for (int n0 = 0; n0 < 8; ++n0)
#pragma unroll
    for (int r = 0; r < 4; ++r) {
      s1[r] += h3[n0][r];
      s2[r] += h3[n0][r] * h3[n0][r];
    }
#pragma unroll
  for (int m = 1; m < 16; m <<= 1) {
#pragma unroll
    for (int r = 0; r < 4; ++r) {
      s1[r] += __shfl_xor(s1[r], m, 64);
      s2[r] += __shfl_xor(s2[r], m, 64);
    }
  }
  float mu[4], rs[4];
#pragma unroll
  for (int r = 0; r < 4; ++r) {
    mu[r] = s1[r] * (1.f / 128.f);
    float var = s2[r] * (1.f / 128.f) - mu[r] * mu[r];
    rs[r] = rsqrtf(var + 1e-5f);
  }
#pragma unroll
  for (int n0 = 0; n0 < 8; ++n0) {
    int col = n0 * 16 + l16;
    float gv = g[col], bv = bg[col];
#pragma unroll
    for (int r = 0; r < 4; ++r) {
      int ni = nbase + quad * 4 + r;
      if (ni < NN) {
        float v = (h3[n0][r] - mu[r]) * rs[r] * gv + bv;
        x_out[(size_t)ni * HD + col] = x[(size_t)ni * HD + col] + v;
      }
    }
  }
}

extern "C" void kernel_launch(void* const* d_in, const int* in_sizes, int n_in,
                              void* d_out, int out_size, void* d_ws, size_t ws_size,
                              hipStream_t stream) {
  const float* x = (const float*)d_in[0];
  const float* e = (const float*)d_in[1];
  const int* idx = (const int*)d_in[2];
  const float* we0 = (const float*)d_in[3];
  const float* be0 = (const float*)d_in[4];
  const float* we1 = (const float*)d_in[5];
  const float* be1 = (const float*)d_in[6];
  const float* we2 = (const float*)d_in[7];
  const float* be2 = (const float*)d_in[8];
  const float* ge = (const float*)d_in[9];
  const float* bge = (const float*)d_in[10];
  const float* wn0 = (const float*)d_in[11];
  const float* bn0 = (const float*)d_in[12];
  const float* wn1 = (const float*)d_in[13];
  const float* bn1 = (const float*)d_in[14];
  const float* wn2 = (const float*)d_in[15];
  const float* bn2 = (const float*)d_in[16];
  const float* gn = (const float*)d_in[17];
  const float* bgn = (const float*)d_in[18];

  float* xout = (float*)d_out;                    // [N,128]
  float* eout = (float*)d_out + (size_t)NN * HD;  // [E,128]

  const size_t WPK = 147456;             // packed weight elems (shorts)
  const size_t XBN = (size_t)NN * HD;    // xb elems (shorts)
  const size_t CSRI = (size_t)NN + (NN + 1) + NN + NE;  // ints
  const size_t WB = WPK * 2, XB = XBN * 2, CSRB = CSRI * 4;

  unsigned short* wpack = (unsigned short*)d_ws;
  unsigned short* w0p = wpack;             // offsets match prep ranges
  unsigned short* w1p = wpack + 49152;
  unsigned short* w2p = wpack + 65536;
  unsigned short* wn0p = wpack + 81920;
  unsigned short* wn1p = wpack + 114688;
  unsigned short* wn2p = wpack + 131072;

  bool use_csr_xb = ws_size >= WB + XB + CSRB;
  bool use_csr = use_csr_xb || ws_size >= WB + CSRB;
  bool use_xb = use_csr_xb || (!use_csr && ws_size >= WB + XB);

  unsigned short* xbuf = wpack + WPK;  // valid when use_xb
  int* ibase = use_xb ? (int*)(wpack + WPK + XBN) : (int*)(wpack + WPK);
  int* cnt = ibase;
  int* offs = cnt + NN;
  int* cur = offs + NN + 1;
  int* perm = cur + NN;

  prep_kernel<<<(997456 + 255) / 256, 256, 0, stream>>>(
      we0, we1, we2, wn0, wn1, wn2, wpack, x, xbuf, cnt, use_csr ? 1 : 0,
      use_xb ? 1 : 0);

  if (use_csr) {
    hist_kernel<<<(NE + 255) / 256, 256, 0, stream>>>(idx, cnt);
    scan_kernel<<<1, 1024, 0, stream>>>(cnt, offs, cur);
    fill_kernel<<<(NE + 255) / 256, 256, 0, stream>>>(idx, cur, perm);
    if (use_xb) {
      edge_kernel<1, 0><<<NE / 64, 256, 0, stream>>>(
          x, xbuf, e, idx, w0p, be0, w1p, be1, w2p, be2, ge, bge, eout, nullptr);
      node_kernel_csr<1><<<(NN + 63) / 64, 256, 0, stream>>>(
          x, xbuf, eout, offs, perm, wn0p, bn0, wn1p, bn1, wn2p, bn2, gn, bgn, xout);
    } else {
      edge_kernel<0, 0><<<NE / 64, 256, 0, stream>>>(
          x, xbuf, e, idx, w0p, be0, w1p, be1, w2p, be2, ge, bge, eout, nullptr);
      node_kernel_csr<0><<<(NN + 63) / 64, 256, 0, stream>>>(
          x, xbuf, eout, offs, perm, wn0p, bn0, wn1p, bn1, wn2p, bn2, gn, bgn, xout);
    }
  } else {
    hipMemsetAsync(xout, 0, (size_t)NN * HD * sizeof(float), stream);
    if (use_xb) {
      edge_kernel<1, 1><<<NE / 64, 256, 0, stream>>>(
          x, xbuf, e, idx, w0p, be0, w1p, be1, w2p, be2, ge, bge, eout, xout);
      node_kernel_atom<1><<<(NN + 63) / 64, 256, 0, stream>>>(
          x, xbuf, xout, wn0p, bn0, wn1p, bn1, wn2p, bn2, gn, bgn, xout);
    } else {
      edge_kernel<0, 1><<<NE / 64, 256, 0, stream>>>(
          x, xbuf, e, idx, w0p, be0, w1p, be1, w2p, be2, ge, bge, eout, xout);
      node_kernel_atom<0><<<(NN + 63) / 64, 256, 0, stream>>>(
          x, xbuf, xout, wn0p, bn0, wn1p, bn1, wn2p, bn2, gn, bgn, xout);
    }
  }
}

// Round 4
// 1011.569 us; speedup vs baseline: 1.1010x; 1.1010x over previous
//
#include <hip/hip_runtime.h>

#define NN 50000
#define NE 600000
#define HD 128

typedef __attribute__((ext_vector_type(8))) short short8;
typedef __attribute__((ext_vector_type(4))) float floatx4;

__device__ __forceinline__ unsigned short f2bf(float f) {
  unsigned int u = __builtin_bit_cast(unsigned int, f);
  u += 0x7FFFu + ((u >> 16) & 1u);
  return (unsigned short)(u >> 16);
}

__device__ __forceinline__ short8 cvt8(const float* __restrict__ p) {
  floatx4 v0 = *(const floatx4*)p;
  floatx4 v1 = *(const floatx4*)(p + 4);
  short8 r;
  r[0] = (short)f2bf(v0[0]); r[1] = (short)f2bf(v0[1]);
  r[2] = (short)f2bf(v0[2]); r[3] = (short)f2bf(v0[3]);
  r[4] = (short)f2bf(v1[0]); r[5] = (short)f2bf(v1[1]);
  r[6] = (short)f2bf(v1[2]); r[7] = (short)f2bf(v1[3]);
  return r;
}

// Pack W[K][128] f32 -> bf16 MFMA B-fragment order (slice k0 = 4096 shorts):
// wp[((k0*8+n0)*64 + lane)*8 + j] = W[k0*32 + (lane>>4)*8 + j][n0*16 + (lane&15)]
__device__ __forceinline__ void pack_one(const float* __restrict__ w,
                                         unsigned short* __restrict__ wp, int p) {
  int j = p & 7, lane = (p >> 3) & 63, t = p >> 9;
  int n0 = t & 7, k0 = t >> 3;
  int k = k0 * 32 + (lane >> 4) * 8 + j;
  int n = n0 * 16 + (lane & 15);
  wp[p] = f2bf(w[k * HD + n]);
}

// Fused prep: pack all 6 weights (edge 20 slices then node 16 slices) +
// zero CSR counters + convert x->bf16.
__global__ void prep_kernel(const float* __restrict__ we0, const float* __restrict__ we1,
                            const float* __restrict__ we2, const float* __restrict__ wn0,
                            const float* __restrict__ wn1, const float* __restrict__ wn2,
                            unsigned short* __restrict__ wpack,
                            const float* __restrict__ x, unsigned short* __restrict__ xb,
                            int* __restrict__ cnt, int do_cnt, int do_cvt) {
  int p = blockIdx.x * 256 + threadIdx.x;
  if (p < 147456) {
    const float* src;
    int rel;
    if (p < 49152) { src = we0; rel = p; }
    else if (p < 65536) { src = we1; rel = p - 49152; }
    else if (p < 81920) { src = we2; rel = p - 65536; }
    else if (p < 114688) { src = wn0; rel = p - 81920; }
    else if (p < 131072) { src = wn1; rel = p - 114688; }
    else { src = wn2; rel = p - 131072; }
    pack_one(src, wpack + (p - rel), rel);
  } else if (p < 197456) {
    if (do_cnt) cnt[p - 147456] = 0;
  } else if (p < 997456) {
    if (do_cvt) {
      int q = p - 197456;
      *(short8*)(xb + (size_t)q * 8) = cvt8(x + (size_t)q * 8);
    }
  }
}

__global__ void hist_kernel(const int* __restrict__ idx, int* __restrict__ cnt) {
  int eid = blockIdx.x * 256 + threadIdx.x;
  if (eid < NE) atomicAdd(&cnt[idx[NE + eid]], 1);
}

// Single-block exclusive scan of cnt[0..NN) -> offs (NN+1) and cur (cursor copy).
// (R2-proven version.)
__global__ __launch_bounds__(1024) void scan_kernel(const int* __restrict__ cnt,
                                                    int* __restrict__ offs,
                                                    int* __restrict__ cur) {
  __shared__ int part[1024];
  int t = threadIdx.x;
  int base = t * 49;
  int s = 0;
  for (int i = 0; i < 49; ++i) {
    int g = base + i;
    if (g < NN) s += cnt[g];
  }
  part[t] = s;
  __syncthreads();
  for (int off = 1; off < 1024; off <<= 1) {
    int add = (t >= off) ? part[t - off] : 0;
    __syncthreads();
    part[t] += add;
    __syncthreads();
  }
  int run = part[t] - s;  // exclusive prefix of this thread's chunk
  for (int i = 0; i < 49; ++i) {
    int g = base + i;
    if (g < NN) {
      int c = cnt[g];
      offs[g] = run;
      cur[g] = run;
      run += c;
    }
  }
  if (t == 1023) offs[NN] = run;
}

__global__ void fill_kernel(const int* __restrict__ idx, int* __restrict__ cur,
                            int* __restrict__ perm) {
  int eid = blockIdx.x * 256 + threadIdx.x;
  if (eid < NE) {
    int d = idx[NE + eid];
    int pos = atomicAdd(&cur[d], 1);
    perm[pos] = eid;
  }
}

__device__ __forceinline__ void store_relu_bf16(const floatx4* acc,
                                                const float* __restrict__ bias,
                                                unsigned short* out_base, int stride,
                                                int lane) {
  int quad = lane >> 4, l16 = lane & 15;
#pragma unroll
  for (int n0 = 0; n0 < 8; ++n0) {
    float bv = bias[n0 * 16 + l16];
#pragma unroll
    for (int r = 0; r < 4; ++r) {
      float v = acc[n0][r] + bv;
      v = v > 0.f ? v : 0.f;
      out_base[(quad * 4 + r) * stride + n0 * 16 + l16] = f2bf(v);
    }
  }
}

#define SH 136  // 128 + 8 pad

// Edge MLP. Weights double-buffered in LDS, one 8KB slice/step, shared by the
// 4 waves. ATOM=1: legacy atomic scatter-add into agg (fallback path).
template <int XBF, int ATOM>
__global__ __launch_bounds__(256, 4) void edge_kernel(
    const float* __restrict__ x, const unsigned short* __restrict__ xb,
    const float* __restrict__ e, const int* __restrict__ idx,
    const unsigned short* __restrict__ wall,  // 20 contiguous 4096-short slices
    const float* __restrict__ b0, const float* __restrict__ b1,
    const float* __restrict__ b2, const float* __restrict__ g,
    const float* __restrict__ bg, float* __restrict__ e_out,
    float* __restrict__ agg) {
  __shared__ __align__(16) unsigned short lh[64 * SH];    // 17408 B
  __shared__ __align__(16) unsigned short wbuf[2][4096];  // 2 x 8 KB

  int tid = threadIdx.x;
  int wave = tid >> 6, lane = tid & 63;
  int quad = lane >> 4, l16 = lane & 15;
  int ebase = blockIdx.x * 64 + wave * 16;
  int arow = ebase + l16;
  int se = idx[arow], de = idx[NE + arow];

  // prologue: stage slice 0
  short8 p0 = *(const short8*)(wall + tid * 16);
  short8 p1 = *(const short8*)(wall + tid * 16 + 8);
  *(short8*)(&wbuf[0][tid * 16]) = p0;
  *(short8*)(&wbuf[0][tid * 16 + 8]) = p1;

  const float* ee = e + (size_t)arow * HD + quad * 8;
  const unsigned short* xd16 = nullptr;
  const unsigned short* xs16 = nullptr;
  const float* xdf = nullptr;
  const float* xsf = nullptr;
  if constexpr (XBF) {
    xd16 = xb + (size_t)de * HD + quad * 8;
    xs16 = xb + (size_t)se * HD + quad * 8;
  } else {
    xdf = x + (size_t)de * HD + quad * 8;
    xsf = x + (size_t)se * HD + quad * 8;
  }
  unsigned short* lhw = lh + wave * 16 * SH;

  floatx4 acc[8];
  floatx4 z = {0.f, 0.f, 0.f, 0.f};
#pragma unroll
  for (int t = 0; t < 8; ++t) acc[t] = z;

  // 20 K-steps: 12 (layer0 K=384) + 4 (layer1) + 4 (layer2)
  for (int s = 0; s < 20; ++s) {
    __syncthreads();  // wbuf[s&1] staged; all waves done reading wbuf[(s+1)&1]
    if (s < 19) {     // issue next-slice loads early; ds_write after MFMA
      p0 = *(const short8*)(wall + (s + 1) * 4096 + tid * 16);
      p1 = *(const short8*)(wall + (s + 1) * 4096 + tid * 16 + 8);
    }
    short8 a;
    if (s < 4) {
      if constexpr (XBF) a = *(const short8*)(xd16 + s * 32);
      else a = cvt8(xdf + s * 32);
    } else if (s < 8) {
      if constexpr (XBF) a = *(const short8*)(xs16 + (s - 4) * 32);
      else a = cvt8(xsf + (s - 4) * 32);
    } else if (s < 12) {
      a = cvt8(ee + (s - 8) * 32);
    } else if (s < 16) {
      a = *(const short8*)(lhw + l16 * SH + (s - 12) * 32 + quad * 8);
    } else {
      a = *(const short8*)(lhw + l16 * SH + (s - 16) * 32 + quad * 8);
    }
    const unsigned short* wsl = &wbuf[s & 1][0];
#pragma unroll
    for (int n0 = 0; n0 < 8; ++n0) {
      short8 b = *(const short8*)(wsl + n0 * 512 + lane * 8);
      acc[n0] = __builtin_amdgcn_mfma_f32_16x16x32_bf16(a, b, acc[n0], 0, 0, 0);
    }
    if (s == 11) {
      store_relu_bf16(acc, b0, lhw, SH, lane);
#pragma unroll
      for (int t = 0; t < 8; ++t) acc[t] = z;
    } else if (s == 15) {
      store_relu_bf16(acc, b1, lhw, SH, lane);
#pragma unroll
      for (int t = 0; t < 8; ++t) acc[t] = z;
    }
    if (s < 19) {
      *(short8*)(&wbuf[(s + 1) & 1][tid * 16]) = p0;
      *(short8*)(&wbuf[(s + 1) & 1][tid * 16 + 8]) = p1;
    }
  }

  // bias + LayerNorm (rows quad*4+r, cols n0*16+l16)
  float h3[8][4];
#pragma unroll
  for (int n0 = 0; n0 < 8; ++n0) {
    float bv = b2[n0 * 16 + l16];
#pragma unroll
    for (int r = 0; r < 4; ++r) h3[n0][r] = acc[n0][r] + bv;
  }
  float s1[4] = {0.f, 0.f, 0.f, 0.f}, s2[4] = {0.f, 0.f, 0.f, 0.f};
#pragma unroll
  for (int n0 = 0; n0 < 8; ++n0)
#pragma unroll
    for (int r = 0; r < 4; ++r) {
      s1[r] += h3[n0][r];
      s2[r] += h3[n0][r] * h3[n0][r];
    }
#pragma unroll
  for (int m = 1; m < 16; m <<= 1) {
#pragma unroll
    for (int r = 0; r < 4; ++r) {
      s1[r] += __shfl_xor(s1[r], m, 64);
      s2[r] += __shfl_xor(s2[r], m, 64);
    }
  }
  float mu[4], rs[4];
#pragma unroll
  for (int r = 0; r < 4; ++r) {
    mu[r] = s1[r] * (1.f / 128.f);
    float var = s2[r] * (1.f / 128.f) - mu[r] * mu[r];
    rs[r] = rsqrtf(var + 1e-5f);
  }
#pragma unroll
  for (int n0 = 0; n0 < 8; ++n0) {
    int col = n0 * 16 + l16;
    float gv = g[col], bv = bg[col];
#pragma unroll
    for (int r = 0; r < 4; ++r) {
      int ei = ebase + quad * 4 + r;
      float v = (h3[n0][r] - mu[r]) * rs[r] * gv + bv;
      e_out[(size_t)ei * HD + col] = v;
      if constexpr (ATOM) {
        int drow = idx[NE + ei];
        atomicAdd(&agg[(size_t)drow * HD + col], v);
      }
    }
  }
}

// Node kernel, CSR path: quad-parallel in-register gather of incoming e_out
// rows (no atomics, no global agg buffer), bf16 rows staged in per-wave LDS,
// then the staged-weight MLP loop (16 K-steps: 8+4+4).
template <int XBF>
__global__ __launch_bounds__(256, 3) void node_kernel_csr(
    const float* __restrict__ x, const unsigned short* __restrict__ xb,
    const float* __restrict__ e_out, const int* __restrict__ offs,
    const int* __restrict__ perm,
    const unsigned short* __restrict__ wall,  // 16 contiguous slices
    const float* __restrict__ b0, const float* __restrict__ b1,
    const float* __restrict__ b2, const float* __restrict__ g,
    const float* __restrict__ bg, float* __restrict__ x_out) {
  __shared__ __align__(16) unsigned short lh[64 * SH];    // 17408 B
  __shared__ __align__(16) unsigned short sag[64 * SH];   // 17408 B
  __shared__ __align__(16) unsigned short wbuf[2][4096];  // 16384 B

  int tid = threadIdx.x;
  int wave = tid >> 6, lane = tid & 63;
  int quad = lane >> 4, l16 = lane & 15;
  int nbase = blockIdx.x * 64 + wave * 16;

  // issue slice-0 weight loads early; gather hides their latency
  short8 p0 = *(const short8*)(wall + tid * 16);
  short8 p1 = *(const short8*)(wall + tid * 16 + 8);

  // --- gather: quad q owns rows q*4..q*4+3; l16 owns cols l16*8..+7 ---
  unsigned short* sagw = sag + wave * 16 * SH;
  for (int rr = 0; rr < 4; ++rr) {
    int rloc = quad * 4 + rr;
    int n = nbase + rloc;
    float a0 = 0.f, a1 = 0.f, a2 = 0.f, a3 = 0.f;
    float a4 = 0.f, a5 = 0.f, a6 = 0.f, a7 = 0.f;
    if (n < NN) {
      int beg = offs[n], end = offs[n + 1];
      int j = beg;
      for (; j + 2 <= end; j += 2) {
        int e0 = perm[j], e1 = perm[j + 1];
        const float* r0 = e_out + (size_t)e0 * HD + l16 * 8;
        const float* r1 = e_out + (size_t)e1 * HD + l16 * 8;
        floatx4 u0 = *(const floatx4*)r0, u1 = *(const floatx4*)(r0 + 4);
        floatx4 w0 = *(const floatx4*)r1, w1 = *(const floatx4*)(r1 + 4);
        a0 += u0[0] + w0[0]; a1 += u0[1] + w0[1];
        a2 += u0[2] + w0[2]; a3 += u0[3] + w0[3];
        a4 += u1[0] + w1[0]; a5 += u1[1] + w1[1];
        a6 += u1[2] + w1[2]; a7 += u1[3] + w1[3];
      }
      if (j < end) {
        int e0 = perm[j];
        const float* r0 = e_out + (size_t)e0 * HD + l16 * 8;
        floatx4 u0 = *(const floatx4*)r0, u1 = *(const floatx4*)(r0 + 4);
        a0 += u0[0]; a1 += u0[1]; a2 += u0[2]; a3 += u0[3];
        a4 += u1[0]; a5 += u1[1]; a6 += u1[2]; a7 += u1[3];
      }
    }
    short8 pk;
    pk[0] = (short)f2bf(a0); pk[1] = (short)f2bf(a1);
    pk[2] = (short)f2bf(a2); pk[3] = (short)f2bf(a3);
    pk[4] = (short)f2bf(a4); pk[5] = (short)f2bf(a5);
    pk[6] = (short)f2bf(a6); pk[7] = (short)f2bf(a7);
    *(short8*)(sagw + rloc * SH + l16 * 8) = pk;  // per-wave region, in-order DS
  }

  // stage slice 0
  *(short8*)(&wbuf[0][tid * 16]) = p0;
  *(short8*)(&wbuf[0][tid * 16 + 8]) = p1;

  int arow = nbase + l16;
  int nc = arow < NN ? arow : NN - 1;
  const unsigned short* xr16 = nullptr;
  const float* xrf = nullptr;
  if constexpr (XBF) xr16 = xb + (size_t)nc * HD + quad * 8;
  else xrf = x + (size_t)nc * HD + quad * 8;
  unsigned short* lhw = lh + wave * 16 * SH;

  floatx4 acc[8];
  floatx4 z = {0.f, 0.f, 0.f, 0.f};
#pragma unroll
  for (int t = 0; t < 8; ++t) acc[t] = z;

  for (int s = 0; s < 16; ++s) {
    __syncthreads();
    if (s < 15) {
      p0 = *(const short8*)(wall + (s + 1) * 4096 + tid * 16);
      p1 = *(const short8*)(wall + (s + 1) * 4096 + tid * 16 + 8);
    }
    short8 a;
    if (s < 4) {
      if constexpr (XBF) a = *(const short8*)(xr16 + s * 32);
      else a = cvt8(xrf + s * 32);
    } else if (s < 8) {
      a = *(const short8*)(sagw + l16 * SH + (s - 4) * 32 + quad * 8);
    } else if (s < 12) {
      a = *(const short8*)(lhw + l16 * SH + (s - 8) * 32 + quad * 8);
    } else {
      a = *(const short8*)(lhw + l16 * SH + (s - 12) * 32 + quad * 8);
    }
    const unsigned short* wsl = &wbuf[s & 1][0];
#pragma unroll
    for (int n0 = 0; n0 < 8; ++n0) {
      short8 b = *(const short8*)(wsl + n0 * 512 + lane * 8);
      acc[n0] = __builtin_amdgcn_mfma_f32_16x16x32_bf16(a, b, acc[n0], 0, 0, 0);
    }
    if (s == 7) {
      store_relu_bf16(acc, b0, lhw, SH, lane);
#pragma unroll
      for (int t = 0; t < 8; ++t) acc[t] = z;
    } else if (s == 11) {
      store_relu_bf16(acc, b1, lhw, SH, lane);
#pragma unroll
      for (int t = 0; t < 8; ++t) acc[t] = z;
    }
    if (s < 15) {
      *(short8*)(&wbuf[(s + 1) & 1][tid * 16]) = p0;
      *(short8*)(&wbuf[(s + 1) & 1][tid * 16 + 8]) = p1;
    }
  }

  float h3[8][4];
#pragma unroll
  for (int n0 = 0; n0 < 8; ++n0) {
    float bv = b2[n0 * 16 + l16];
#pragma unroll
    for (int r = 0; r < 4; ++r) h3[n0][r] = acc[n0][r] + bv;
  }
  float s1[4] = {0.f, 0.f, 0.f, 0.f}, s2[4] = {0.f, 0.f, 0.f, 0.f};
#pragma unroll
  for (int n0 = 0; n0 < 8; ++n0)
#pragma unroll
    for (int r = 0; r < 4; ++r) {
      s1[r] += h3[n0][r];
      s2[r] += h3[n0][r] * h3[n0][r];
    }
#pragma unroll
  for (int m = 1; m < 16; m <<= 1) {
#pragma unroll
    for (int r = 0; r < 4; ++r) {
      s1[r] += __shfl_xor(s1[r], m, 64);
      s2[r] += __shfl_xor(s2[r], m, 64);
    }
  }
  float mu[4], rs[4];
#pragma unroll
  for (int r = 0; r < 4; ++r) {
    mu[r] = s1[r] * (1.f / 128.f);
    float var = s2[r] * (1.f / 128.f) - mu[r] * mu[r];
    rs[r] = rsqrtf(var + 1e-5f);
  }
#pragma unroll
  for (int n0 = 0; n0 < 8; ++n0) {
    int col = n0 * 16 + l16;
    float gv = g[col], bv = bg[col];
#pragma unroll
    for (int r = 0; r < 4; ++r) {
      int ni = nbase + quad * 4 + r;
      if (ni < NN) {
        float v = (h3[n0][r] - mu[r]) * rs[r] * gv + bv;
        x_out[(size_t)ni * HD + col] = x[(size_t)ni * HD + col] + v;
      }
    }
  }
}

// Node kernel, ATOM fallback: reads a pre-accumulated global agg array.
template <int XBF>
__global__ __launch_bounds__(256, 4) void node_kernel_agg(
    const float* __restrict__ x, const unsigned short* __restrict__ xb,
    const float* __restrict__ agg,
    const unsigned short* __restrict__ wall,
    const float* __restrict__ b0, const float* __restrict__ b1,
    const float* __restrict__ b2, const float* __restrict__ g,
    const float* __restrict__ bg, float* __restrict__ x_out) {
  __shared__ __align__(16) unsigned short lh[64 * SH];
  __shared__ __align__(16) unsigned short wbuf[2][4096];

  int tid = threadIdx.x;
  int wave = tid >> 6, lane = tid & 63;
  int quad = lane >> 4, l16 = lane & 15;
  int nbase = blockIdx.x * 64 + wave * 16;
  int arow = nbase + l16;
  int nc = arow < NN ? arow : NN - 1;

  short8 p0 = *(const short8*)(wall + tid * 16);
  short8 p1 = *(const short8*)(wall + tid * 16 + 8);
  *(short8*)(&wbuf[0][tid * 16]) = p0;
  *(short8*)(&wbuf[0][tid * 16 + 8]) = p1;

  const float* ar = agg + (size_t)nc * HD + quad * 8;
  const unsigned short* xr16 = nullptr;
  const float* xrf = nullptr;
  if constexpr (XBF) xr16 = xb + (size_t)nc * HD + quad * 8;
  else xrf = x + (size_t)nc * HD + quad * 8;
  unsigned short* lhw = lh + wave * 16 * SH;

  floatx4 acc[8];
  floatx4 z = {0.f, 0.f, 0.f, 0.f};
#pragma unroll
  for (int t = 0; t < 8; ++t) acc[t] = z;

  for (int s = 0; s < 16; ++s) {
    __syncthreads();
    if (s < 15) {
      p0 = *(const short8*)(wall + (s + 1) * 4096 + tid * 16);
      p1 = *(const short8*)(wall + (s + 1) * 4096 + tid * 16 + 8);
    }
    short8 a;
    if (s < 4) {
      if constexpr (XBF) a = *(const short8*)(xr16 + s * 32);
      else a = cvt8(xrf + s * 32);
    } else if (s < 8) {
      a = cvt8(ar + (s - 4) * 32);
    } else if (s < 12) {
      a = *(const short8*)(lhw + l16 * SH + (s - 8) * 32 + quad * 8);
    } else {
      a = *(const short8*)(lhw + l16 * SH + (s - 12) * 32 + quad * 8);
    }
    const unsigned short* wsl = &wbuf[s & 1][0];
#pragma unroll
    for (int n0 = 0; n0 < 8; ++n0) {
      short8 b = *(const short8*)(wsl + n0 * 512 + lane * 8);
      acc[n0] = __builtin_amdgcn_mfma_f32_16x16x32_bf16(a, b, acc[n0], 0, 0, 0);
    }
    if (s == 7) {
      store_relu_bf16(acc, b0, lhw, SH, lane);
#pragma unroll
      for (int t = 0; t < 8; ++t) acc[t] = z;
    } else if (s == 11) {
      store_relu_bf16(acc, b1, lhw, SH, lane);
#pragma unroll
      for (int t = 0; t < 8; ++t) acc[t] = z;
    }
    if (s < 15) {
      *(short8*)(&wbuf[(s + 1) & 1][tid * 16]) = p0;
      *(short8*)(&wbuf[(s + 1) & 1][tid * 16 + 8]) = p1;
    }
  }

  float h3[8][4];
#pragma unroll
  for (int n0 = 0; n0 < 8; ++n0) {
    float bv = b2[n0 * 16 + l16];
#pragma unroll
    for (int r = 0; r < 4; ++r) h3[n0][r] = acc[n0][r] + bv;
  }
  float s1[4] = {0.f, 0.f, 0.f, 0.f}, s2[4] = {0.f, 0.f, 0.f, 0.f};
#pragma unroll
  for (int n0 = 0; n0 < 8; ++n0)
#pragma unroll
    for (int r = 0; r < 4; ++r) {
      s1[r] += h3[n0][r];
      s2[r] += h3[n0][r] * h3[n0][r];
    }
#pragma unroll
  for (int m = 1; m < 16; m <<= 1) {
#pragma unroll
    for (int r = 0; r < 4; ++r) {
      s1[r] += __shfl_xor(s1[r], m, 64);
      s2[r] += __shfl_xor(s2[r], m, 64);
    }
  }
  float mu[4], rs[4];
#pragma unroll
  for (int r = 0; r < 4; ++r) {
    mu[r] = s1[r] * (1.f / 128.f);
    float var = s2[r] * (1.f / 128.f) - mu[r] * mu[r];
    rs[r] = rsqrtf(var + 1e-5f);
  }
#pragma unroll
  for (int n0 = 0; n0 < 8; ++n0) {
    int col = n0 * 16 + l16;
    float gv = g[col], bv = bg[col];
#pragma unroll
    for (int r = 0; r < 4; ++r) {
      int ni = nbase + quad * 4 + r;
      if (ni < NN) {
        float v = (h3[n0][r] - mu[r]) * rs[r] * gv + bv;
        x_out[(size_t)ni * HD + col] = x[(size_t)ni * HD + col] + v;
      }
    }
  }
}

extern "C" void kernel_launch(void* const* d_in, const int* in_sizes, int n_in,
                              void* d_out, int out_size, void* d_ws, size_t ws_size,
                              hipStream_t stream) {
  const float* x = (const float*)d_in[0];
  const float* e = (const float*)d_in[1];
  const int* idx = (const int*)d_in[2];
  const float* we0 = (const float*)d_in[3];
  const float* be0 = (const float*)d_in[4];
  const float* we1 = (const float*)d_in[5];
  const float* be1 = (const float*)d_in[6];
  const float* we2 = (const float*)d_in[7];
  const float* be2 = (const float*)d_in[8];
  const float* ge = (const float*)d_in[9];
  const float* bge = (const float*)d_in[10];
  const float* wn0 = (const float*)d_in[11];
  const float* bn0 = (const float*)d_in[12];
  const float* wn1 = (const float*)d_in[13];
  const float* bn1 = (const float*)d_in[14];
  const float* wn2 = (const float*)d_in[15];
  const float* bn2 = (const float*)d_in[16];
  const float* gn = (const float*)d_in[17];
  const float* bgn = (const float*)d_in[18];

  float* xout = (float*)d_out;                    // [N,128]
  float* eout = (float*)d_out + (size_t)NN * HD;  // [E,128]

  const size_t WPK = 147456;           // packed weight shorts
  const size_t XBN = (size_t)NN * HD;  // xb shorts
  const size_t CSRI = (size_t)NN + (NN + 1) + NN + NE;  // cnt, offs, cur, perm
  const size_t WB = WPK * 2, XB = XBN * 2, CSRB = CSRI * 4;

  unsigned short* wpack = (unsigned short*)d_ws;
  const unsigned short* wedge = wpack;          // 20 slices (we0,we1,we2)
  const unsigned short* wnode = wpack + 81920;  // 16 slices (wn0,wn1,wn2)

  bool full = ws_size >= WB + XB + CSRB;  // ~16.1 MB
  bool use_csr = full || ws_size >= WB + CSRB;
  bool use_xb = full || (!use_csr && ws_size >= WB + XB);

  unsigned short* xbuf = wpack + WPK;
  int* ibase = (int*)(wpack + WPK + (use_xb ? XBN : 0));
  int* cnt = ibase;
  int* offs = cnt + NN;
  int* cur = offs + NN + 1;
  int* perm = cur + NN;

  prep_kernel<<<(997456 + 255) / 256, 256, 0, stream>>>(
      we0, we1, we2, wn0, wn1, wn2, wpack, x, xbuf, cnt, use_csr ? 1 : 0,
      use_xb ? 1 : 0);

  if (use_csr) {
    hist_kernel<<<(NE + 255) / 256, 256, 0, stream>>>(idx, cnt);
    scan_kernel<<<1, 1024, 0, stream>>>(cnt, offs, cur);
    fill_kernel<<<(NE + 255) / 256, 256, 0, stream>>>(idx, cur, perm);
    if (full) {
      edge_kernel<1, 0><<<NE / 64, 256, 0, stream>>>(
          x, xbuf, e, idx, wedge, be0, be1, be2, ge, bge, eout, nullptr);
      node_kernel_csr<1><<<(NN + 63) / 64, 256, 0, stream>>>(
          x, xbuf, eout, offs, perm, wnode, bn0, bn1, bn2, gn, bgn, xout);
    } else {
      edge_kernel<0, 0><<<NE / 64, 256, 0, stream>>>(
          x, xbuf, e, idx, wedge, be0, be1, be2, ge, bge, eout, nullptr);
      node_kernel_csr<0><<<(NN + 63) / 64, 256, 0, stream>>>(
          x, xbuf, eout, offs, perm, wnode, bn0, bn1, bn2, gn, bgn, xout);
    }
  } else {
    hipMemsetAsync(xout, 0, (size_t)NN * HD * sizeof(float), stream);  // agg = 0
    if (use_xb) {
      edge_kernel<1, 1><<<NE / 64, 256, 0, stream>>>(
          x, xbuf, e, idx, wedge, be0, be1, be2, ge, bge, eout, xout);
      node_kernel_agg<1><<<(NN + 63) / 64, 256, 0, stream>>>(
          x, xbuf, xout, wnode, bn0, bn1, bn2, gn, bgn, xout);
    } else {
      edge_kernel<0, 1><<<NE / 64, 256, 0, stream>>>(
          x, xbuf, e, idx, wedge, be0, be1, be2, ge, bge, eout, xout);
      node_kernel_agg<0><<<(NN + 63) / 64, 256, 0, stream>>>(
          x, xbuf, xout, wnode, bn0, bn1, bn2, gn, bgn, xout);
    }
  }
}